// Round 7
// baseline (283.589 us; speedup 1.0000x reference)
//
#include <hip/hip_runtime.h>

#define B_SZ   4
#define N_SEQ  2048
#define DIM    1024
#define H_N    16
#define DH     64
#define INNER  1024
#define M_TOK  8192
// SCALE * log2(e): folded into Q in qkv_gemm epilogue so attn uses exp2 directly
#define QSCALE 0.1803368801111244f

typedef __attribute__((ext_vector_type(8))) short bf16x8;
typedef __attribute__((ext_vector_type(4))) float f32x4;

__device__ __forceinline__ unsigned short f2b(float f) {
  union { float f; unsigned u; } v; v.f = f;
  unsigned r = v.u + 0x7fffu + ((v.u >> 16) & 1u);
  return (unsigned short)(r >> 16);
}

// async global->LDS, 16B per lane; LDS dest is wave-uniform base + lane*16
__device__ __forceinline__ void gl_lds16(const unsigned short* g, unsigned short* l) {
  __builtin_amdgcn_global_load_lds((const __attribute__((address_space(1))) void*)g,
                                   (__attribute__((address_space(3))) void*)l, 16, 0, 0);
}

// ---------------- x fp32 -> bf16 ----------------
__global__ __launch_bounds__(256) void cast_x(const float* __restrict__ x,
                                              unsigned short* __restrict__ xb) {
  int i = (blockIdx.x * 256 + threadIdx.x) * 4;
  float4 v = *(const float4*)(x + i);
  ushort4 o;
  o.x = f2b(v.x); o.y = f2b(v.y); o.z = f2b(v.z); o.w = f2b(v.w);
  *(ushort4*)(xb + i) = o;
}

// ---------------- W -> W^T bf16 (4 weights) ----------------
__global__ __launch_bounds__(256) void trans_w(const float* __restrict__ Wq,
    const float* __restrict__ Wk, const float* __restrict__ Wv,
    const float* __restrict__ Wo, unsigned short* __restrict__ WT) {
  const int z = blockIdx.z;
  const float* W = (z == 0) ? Wq : (z == 1) ? Wk : (z == 2) ? Wv : Wo;
  unsigned short* T = WT + (size_t)z * DIM * INNER;
  __shared__ float tile[64][65];
  const int n0 = blockIdx.x * 64, k0 = blockIdx.y * 64;
  const int tid = threadIdx.x;
#pragma unroll
  for (int it = 0; it < 16; it++) {
    int lin = it * 256 + tid;
    int r = lin >> 6, c = lin & 63;
    tile[r][c] = W[(size_t)(k0 + r) * 1024 + n0 + c];
  }
  __syncthreads();
#pragma unroll
  for (int it = 0; it < 16; it++) {
    int lin = it * 256 + tid;
    int r = lin >> 6, c = lin & 63;
    T[(size_t)(n0 + r) * 1024 + k0 + c] = f2b(tile[c][r]);
  }
}

// ---------------- QKV projection GEMM (m97-style, BK=64, XCD-swizzled) ------
// grid (24, 64): blockIdx.x = z*8 + n-tile (XCD = idx%8 = n-tile -> each XCD
// reads only its own weight n-slices); blockIdx.y = m-tile.
// z==0/1: Q/K written token-major [m][1024] (Q pre-scaled by QSCALE).
// z==2:   V written TRANSPOSED as V^T [bh][dh][n] with packed b64 stores.
__global__ __launch_bounds__(256) void qkv_gemm(const unsigned short* __restrict__ xb,
    const unsigned short* __restrict__ WT, unsigned short* __restrict__ QKV) {
  __shared__ __align__(16) unsigned short As[2 * 128 * 32];
  __shared__ __align__(16) unsigned short Bs[2 * 128 * 32];
  const int tid = threadIdx.x;
  const int lane = tid & 63, wv = tid >> 6;
  const int quad = lane >> 4, l16 = lane & 15;
  const int wm = wv >> 1, wn = wv & 1;
  const int z = blockIdx.x >> 3;
  const int m0 = blockIdx.y * 128, n0 = (blockIdx.x & 7) * 128;
  const unsigned short* Ag = xb + (size_t)m0 * DIM;
  const unsigned short* Bg = WT + (size_t)z * DIM * INNER + (size_t)n0 * DIM;
  unsigned short* Out = QKV + (size_t)z * M_TOK * INNER;

  f32x4 zero = {0.f, 0.f, 0.f, 0.f};
  f32x4 acc[4][4];
#pragma unroll
  for (int i = 0; i < 4; i++)
#pragma unroll
    for (int j = 0; j < 4; j++) acc[i][j] = zero;

  const int lr = lane >> 2, lc = (lane & 3) * 8;
  const int c0 = wv * 2, c1 = wv * 2 + 1;

  for (int k0 = 0; k0 < DIM; k0 += 64) {
    __syncthreads();
#pragma unroll
    for (int h = 0; h < 2; h++) {
      gl_lds16(&Ag[(size_t)(c0 * 16 + lr) * DIM + k0 + h * 32 + lc], &As[h * 4096 + c0 * 512]);
      gl_lds16(&Ag[(size_t)(c1 * 16 + lr) * DIM + k0 + h * 32 + lc], &As[h * 4096 + c1 * 512]);
      gl_lds16(&Bg[(size_t)(c0 * 16 + lr) * DIM + k0 + h * 32 + lc], &Bs[h * 4096 + c0 * 512]);
      gl_lds16(&Bg[(size_t)(c1 * 16 + lr) * DIM + k0 + h * 32 + lc], &Bs[h * 4096 + c1 * 512]);
    }
    __syncthreads();
#pragma unroll
    for (int h = 0; h < 2; h++) {
      bf16x8 af[4], bfr[4];
#pragma unroll
      for (int i = 0; i < 4; i++)
        af[i] = *(const bf16x8*)&As[h * 4096 + (wm * 64 + i * 16 + l16) * 32 + quad * 8];
#pragma unroll
      for (int j = 0; j < 4; j++)
        bfr[j] = *(const bf16x8*)&Bs[h * 4096 + (wn * 64 + j * 16 + l16) * 32 + quad * 8];
#pragma unroll
      for (int i = 0; i < 4; i++)
#pragma unroll
        for (int j = 0; j < 4; j++)
          acc[i][j] = __builtin_amdgcn_mfma_f32_16x16x32_bf16(af[i], bfr[j], acc[i][j], 0, 0, 0);
    }
  }
  if (z != 2) {
    const float cs = (z == 0) ? QSCALE : 1.0f;
#pragma unroll
    for (int i = 0; i < 4; i++) {
#pragma unroll
      for (int j = 0; j < 4; j++) {
        int n = n0 + wn * 64 + j * 16 + l16;
#pragma unroll
        for (int r = 0; r < 4; r++) {
          int m = m0 + wm * 64 + i * 16 + quad * 4 + r;
          Out[(size_t)m * INNER + n] = f2b(acc[i][j][r] * cs);
        }
      }
    }
  } else {
#pragma unroll
    for (int i = 0; i < 4; i++) {
#pragma unroll
      for (int j = 0; j < 4; j++) {
        int n = n0 + wn * 64 + j * 16 + l16;
        int h = n >> 6, dh = n & 63;
        int mbase = m0 + wm * 64 + i * 16 + quad * 4;
        int b = mbase >> 11, nq = mbase & 2047;
        unsigned lo = (unsigned)f2b(acc[i][j][0]) | ((unsigned)f2b(acc[i][j][1]) << 16);
        unsigned hi = (unsigned)f2b(acc[i][j][2]) | ((unsigned)f2b(acc[i][j][3]) << 16);
        uint2 pw; pw.x = lo; pw.y = hi;
        *(uint2*)&Out[((size_t)(b * H_N + h) * DH + dh) * N_SEQ + nq] = pw;
      }
    }
  }
}

// ---------------- flash attention (XCD-swizzled grid) ----------------
// grid (64, 16): blockIdx.x = bh (fast) -> XCD = bh%8; all 16 q-tiles of a bh
// share one XCD's L2, so K/VT slices are fetched ~once (entire grid is
// co-resident at 4 blocks/CU).
#define KT 64
#define LSTR 72

__global__ __launch_bounds__(256, 4) void attn(const unsigned short* __restrict__ Q,
    const unsigned short* __restrict__ K, const unsigned short* __restrict__ VT,
    unsigned short* __restrict__ O) {
  __shared__ __align__(16) unsigned short Ks[KT * LSTR];
  __shared__ __align__(16) unsigned short VTs[DH * LSTR];
  __shared__ __align__(16) unsigned short Ps[128 * LSTR];
  const int tid = threadIdx.x;
  const int lane = tid & 63, w = tid >> 6;
  const int quad = lane >> 4, l16 = lane & 15;
  const int qh = w & 1, kh = w >> 1;
  const int bh = blockIdx.x;
  const int b = bh >> 4, h = bh & 15;
  const int q0 = blockIdx.y * 128;
  const unsigned short* Qp = Q + ((size_t)b * N_SEQ) * INNER + h * DH;
  const unsigned short* Kp = K + ((size_t)b * N_SEQ) * INNER + h * DH;
  const unsigned short* VTp = VT + (size_t)bh * DH * N_SEQ;

  bf16x8 aq[4][2];
#pragma unroll
  for (int qi = 0; qi < 4; qi++) {
    const unsigned short* qr = Qp + (size_t)(q0 + qh * 64 + qi * 16 + l16) * INNER;
    aq[qi][0] = *(const bf16x8*)&qr[quad * 8];
    aq[qi][1] = *(const bf16x8*)&qr[32 + quad * 8];
  }

  bf16x8 vone;
#pragma unroll
  for (int j = 0; j < 8; j++) vone[j] = (short)0x3F80;

  f32x4 zero = {0.f, 0.f, 0.f, 0.f};
  f32x4 oacc[2][4];
  f32x4 lacc[2];
#pragma unroll
  for (int mi = 0; mi < 2; mi++) {
    lacc[mi] = zero;
#pragma unroll
    for (int t = 0; t < 4; t++) oacc[mi][t] = zero;
  }

  const int srow = tid >> 3, scol = (tid & 7) * 8;

  for (int k0 = 0; k0 < N_SEQ; k0 += KT) {
    __syncthreads();
#pragma unroll
    for (int p = 0; p < 2; p++)
      *(uint4*)&Ks[(p * 32 + srow) * LSTR + scol] =
          *(const uint4*)&Kp[(size_t)(k0 + p * 32 + srow) * INNER + scol];
#pragma unroll
    for (int p = 0; p < 2; p++)
      *(uint4*)&VTs[(p * 32 + srow) * LSTR + scol] =
          *(const uint4*)&VTp[(size_t)(p * 32 + srow) * N_SEQ + k0 + scol];
    __syncthreads();

    f32x4 s[2][4];
#pragma unroll
    for (int t = 0; t < 2; t++)
#pragma unroll
      for (int qi = 0; qi < 4; qi++) s[t][qi] = zero;
#pragma unroll
    for (int kk = 0; kk < 2; kk++) {
#pragma unroll
      for (int t = 0; t < 2; t++) {
        bf16x8 ka = *(const bf16x8*)&Ks[(kh * 32 + t * 16 + l16) * LSTR + kk * 32 + quad * 8];
#pragma unroll
        for (int qi = 0; qi < 4; qi++)
          s[t][qi] = __builtin_amdgcn_mfma_f32_16x16x32_bf16(ka, aq[qi][kk], s[t][qi], 0, 0, 0);
      }
    }

#pragma unroll
    for (int t = 0; t < 2; t++) {
#pragma unroll
      for (int qi = 0; qi < 4; qi++) {
#pragma unroll
        for (int r = 0; r < 4; r++)
          s[t][qi][r] = __builtin_amdgcn_exp2f(s[t][qi][r]);
        unsigned lo = (__float_as_uint(s[t][qi][0]) >> 16) |
                      (__float_as_uint(s[t][qi][1]) & 0xffff0000u);
        unsigned hi = (__float_as_uint(s[t][qi][2]) >> 16) |
                      (__float_as_uint(s[t][qi][3]) & 0xffff0000u);
        uint2 pw; pw.x = lo; pw.y = hi;
        *(uint2*)&Ps[(qh * 64 + qi * 16 + l16) * LSTR + kh * 32 + t * 16 + quad * 4] = pw;
      }
    }
    __syncthreads();

#pragma unroll
    for (int kk2 = 0; kk2 < 2; kk2++) {
      bf16x8 pf0 = *(const bf16x8*)&Ps[(w * 32 + l16) * LSTR + kk2 * 32 + quad * 8];
      bf16x8 pf1 = *(const bf16x8*)&Ps[(w * 32 + 16 + l16) * LSTR + kk2 * 32 + quad * 8];
      lacc[0] = __builtin_amdgcn_mfma_f32_16x16x32_bf16(pf0, vone, lacc[0], 0, 0, 0);
      lacc[1] = __builtin_amdgcn_mfma_f32_16x16x32_bf16(pf1, vone, lacc[1], 0, 0, 0);
#pragma unroll
      for (int t2 = 0; t2 < 4; t2++) {
        bf16x8 vf = *(const bf16x8*)&VTs[(t2 * 16 + l16) * LSTR + kk2 * 32 + quad * 8];
        oacc[0][t2] = __builtin_amdgcn_mfma_f32_16x16x32_bf16(pf0, vf, oacc[0][t2], 0, 0, 0);
        oacc[1][t2] = __builtin_amdgcn_mfma_f32_16x16x32_bf16(pf1, vf, oacc[1][t2], 0, 0, 0);
      }
    }
  }

#pragma unroll
  for (int mi = 0; mi < 2; mi++) {
#pragma unroll
    for (int r = 0; r < 4; r++) {
      float rl = __builtin_amdgcn_rcpf(lacc[mi][r]);
      int qrow = q0 + w * 32 + mi * 16 + quad * 4 + r;
#pragma unroll
      for (int t2 = 0; t2 < 4; t2++) {
        int col = h * DH + t2 * 16 + l16;
        O[((size_t)b * N_SEQ + qrow) * INNER + col] = f2b(oacc[mi][t2][r] * rl);
      }
    }
  }
}

// ---------------- output GEMM: 128x64 tile, BK=64, grid (64,16)=1024 blocks -
// out = O @ Wo + bo (fp32 out). Wave tile 64m x 32n (2x2 waves).
__global__ __launch_bounds__(256) void out_gemm(const unsigned short* __restrict__ Ob,
    const unsigned short* __restrict__ WoT, const float* __restrict__ bo,
    float* __restrict__ out) {
  __shared__ __align__(16) unsigned short As[2 * 128 * 32];
  __shared__ __align__(16) unsigned short Bs[2 * 64 * 32];
  const int tid = threadIdx.x;
  const int lane = tid & 63, wv = tid >> 6;
  const int quad = lane >> 4, l16 = lane & 15;
  const int wm = wv >> 1, wn = wv & 1;
  const int m0 = blockIdx.x * 128, n0 = blockIdx.y * 64;
  const unsigned short* Ag = Ob + (size_t)m0 * INNER;
  const unsigned short* Bg = WoT + (size_t)n0 * INNER;

  f32x4 zero = {0.f, 0.f, 0.f, 0.f};
  f32x4 acc[4][2];
#pragma unroll
  for (int i = 0; i < 4; i++)
#pragma unroll
    for (int j = 0; j < 2; j++) acc[i][j] = zero;

  const int lr = lane >> 2, lc = (lane & 3) * 8;
  const int c0 = wv * 2, c1 = wv * 2 + 1;
  const int cb = wv;

  for (int k0 = 0; k0 < INNER; k0 += 64) {
    __syncthreads();
#pragma unroll
    for (int h = 0; h < 2; h++) {
      gl_lds16(&Ag[(size_t)(c0 * 16 + lr) * INNER + k0 + h * 32 + lc], &As[h * 4096 + c0 * 512]);
      gl_lds16(&Ag[(size_t)(c1 * 16 + lr) * INNER + k0 + h * 32 + lc], &As[h * 4096 + c1 * 512]);
      gl_lds16(&Bg[(size_t)(cb * 16 + lr) * INNER + k0 + h * 32 + lc], &Bs[h * 2048 + cb * 512]);
    }
    __syncthreads();
#pragma unroll
    for (int h = 0; h < 2; h++) {
      bf16x8 af[4], bfr[2];
#pragma unroll
      for (int i = 0; i < 4; i++)
        af[i] = *(const bf16x8*)&As[h * 4096 + (wm * 64 + i * 16 + l16) * 32 + quad * 8];
#pragma unroll
      for (int j = 0; j < 2; j++)
        bfr[j] = *(const bf16x8*)&Bs[h * 2048 + (wn * 32 + j * 16 + l16) * 32 + quad * 8];
#pragma unroll
      for (int i = 0; i < 4; i++)
#pragma unroll
        for (int j = 0; j < 2; j++)
          acc[i][j] = __builtin_amdgcn_mfma_f32_16x16x32_bf16(af[i], bfr[j], acc[i][j], 0, 0, 0);
    }
  }
#pragma unroll
  for (int i = 0; i < 4; i++) {
#pragma unroll
    for (int j = 0; j < 2; j++) {
      int n = n0 + wn * 32 + j * 16 + l16;
      float bias = bo[n];
#pragma unroll
      for (int r = 0; r < 4; r++) {
        int m = m0 + wm * 64 + i * 16 + quad * 4 + r;
        out[(size_t)m * DIM + n] = acc[i][j][r] + bias;
      }
    }
  }
}

extern "C" void kernel_launch(void* const* d_in, const int* in_sizes, int n_in,
                              void* d_out, int out_size, void* d_ws, size_t ws_size,
                              hipStream_t stream) {
  const float* x  = (const float*)d_in[0];
  const float* Wq = (const float*)d_in[1];
  const float* Wk = (const float*)d_in[2];
  const float* Wv = (const float*)d_in[3];
  const float* Wo = (const float*)d_in[4];
  const float* bo = (const float*)d_in[5];

  char* ws = (char*)d_ws;
  unsigned short* xb   = (unsigned short*)ws;                       // 16 MiB
  unsigned short* WT   = (unsigned short*)(ws + (size_t)16777216);  // 8 MiB
  unsigned short* QKV  = (unsigned short*)(ws + (size_t)25165824);  // 48 MiB: Q,K tok-major + V^T
  unsigned short* Obuf = (unsigned short*)(ws + (size_t)75497472);  // 16 MiB

  cast_x<<<dim3(8192), 256, 0, stream>>>(x, xb);
  trans_w<<<dim3(16, 16, 4), 256, 0, stream>>>(Wq, Wk, Wv, Wo, WT);
  qkv_gemm<<<dim3(24, 64), 256, 0, stream>>>(xb, WT, QKV);
  attn<<<dim3(64, 16), 256, 0, stream>>>(QKV,
                                         QKV + (size_t)M_TOK * INNER,
                                         QKV + (size_t)2 * M_TOK * INNER,
                                         Obuf);
  out_gemm<<<dim3(64, 16), 256, 0, stream>>>(Obuf, WT + (size_t)3 * DIM * INNER, bo,
                                             (float*)d_out);
}